// Round 3
// baseline (491.995 us; speedup 1.0000x reference)
//
#include <hip/hip_runtime.h>

// EKF_v2: B=16384, N=128, DX=5, DZ=2.
// Block = 128 threads = 2 waves; each WAVE owns one batch (64 lanes,
// 2 particles/lane: p = l and l+64). All reductions are in-wave butterflies.
// No launch_bounds min-wave forcing (round-2 spill lesson); tiny LDS footprint;
// direct global loads/stores for state/y/out (line-covering access).

#define BPB 2

__global__ __launch_bounds__(128) void ekf_fused(
    const float* __restrict__ state_old,  // (B,128,5)
    const float* __restrict__ y_obs,      // (B,128,2)
    const float* __restrict__ encoding,   // (B,128)
    const float* __restrict__ pw1,        // (2,16)
    const float* __restrict__ pb1,        // (16)
    const float* __restrict__ pw2,        // (16,32)
    const float* __restrict__ pb2,        // (32)
    const float* __restrict__ pw3,        // (32,2)
    const float* __restrict__ pb3,        // (2)
    const float* __restrict__ nw1,        // (128,32)
    const float* __restrict__ nb1,        // (32)
    const float* __restrict__ nw2,        // (32,2)
    const float* __restrict__ nb2,        // (2)
    const float* __restrict__ lob,        // (2)
    const float* __restrict__ fob,        // (2)
    float* __restrict__ out)              // (B,128,5)
{
    __shared__ __align__(16) float s_enc[BPB * 128];
    __shared__ __align__(16) float s_pw2t[512]; // [j][k] = pw2[k][j]
    __shared__ float s_pw1[32];
    __shared__ float s_pb1[16];
    __shared__ float s_pb2[32];
    __shared__ float s_pw3[64];
    __shared__ float s_nb1[32];
    __shared__ float s_nw2[64];
    __shared__ float s_pb3[2];
    __shared__ float s_nb2[2];
    __shared__ float s_bias[4]; // lob0, lob1, fob0, fob1

    const int t = threadIdx.x;
    const int base = blockIdx.x * BPB;

    // ---- stage encoding + weights (tiny) ----
    {
        const float4* se = (const float4*)(encoding + (size_t)base * 128);
        float4* de = (float4*)s_enc;
        if (t < BPB * 32) de[t] = se[t];
    }
    if (t < 32) { s_pw1[t] = pw1[t]; s_pb2[t] = pb2[t]; s_nb1[t] = nb1[t]; }
    if (t < 16) s_pb1[t] = pb1[t];
    if (t < 64) { s_pw3[t] = pw3[t]; s_nw2[t] = nw2[t]; }
    if (t < 2)  { s_pb3[t] = pb3[t]; s_nb2[t] = nb2[t]; s_bias[t] = lob[t]; s_bias[2 + t] = fob[t]; }
    #pragma unroll
    for (int i = t; i < 512; i += 128) { int jj = i >> 4, k = i & 15; s_pw2t[i] = pw2[k * 32 + jj]; }
    __syncthreads();

    const int w = t >> 6;   // wave index = batch within block
    const int l = t & 63;   // lane
    const size_t b = (size_t)base + w;

    // ---- noise MLP partial sums (4 indep chains; k split across lane-halves) ----
    const int j = l & 31;
    const int kh = (l & 32) << 1; // 0 or 64
    float na0 = 0.f, na1 = 0.f, na2 = 0.f, na3 = 0.f;
    {
        const float* eg = s_enc + w * 128 + kh;
        const float* wp = nw1 + (size_t)kh * 32 + j;
        #pragma unroll 8
        for (int k = 0; k < 64; k += 4) {
            na0 = fmaf(eg[k + 0], wp[(k + 0) * 32], na0);
            na1 = fmaf(eg[k + 1], wp[(k + 1) * 32], na1);
            na2 = fmaf(eg[k + 2], wp[(k + 2) * 32], na2);
            na3 = fmaf(eg[k + 3], wp[(k + 3) * 32], na3);
        }
    }

    // ---- process model: 2 particles/lane (p = l, l+64), direct global reads ----
    float xp[2][5];
    float h1[2][16];
    #pragma unroll
    for (int m = 0; m < 2; ++m) {
        const float* s = state_old + (b * 128 + (size_t)(l + 64 * m)) * 5;
        float s0 = s[0], s1 = s[1], s2 = s[2], v = s[3], td = s[4];
        float theta = s2 + td;
        float sn, cs;
        __sincosf(theta, &sn, &cs);
        xp[m][0] = fmaf(v, sn, s0);
        xp[m][1] = fmaf(v, cs, s1);
        xp[m][2] = theta;
        xp[m][3] = v;
        xp[m][4] = td;
        #pragma unroll
        for (int q = 0; q < 16; ++q)
            h1[m][q] = fmaxf(0.0f, fmaf(v, s_pw1[q], fmaf(td, s_pw1[16 + q], s_pb1[q])));
    }

    // ---- layers 2+3 fused (weights broadcast from LDS, amortized over 2 m) ----
    float o3[2] = {0.f, 0.f}, o4[2] = {0.f, 0.f};
    const float4* w2v = (const float4*)s_pw2t;
    #pragma unroll
    for (int jj = 0; jj < 32; ++jj) {
        float acc0 = s_pb2[jj], acc1 = s_pb2[jj];
        #pragma unroll
        for (int q = 0; q < 4; ++q) {
            float4 wv = w2v[jj * 4 + q];
            acc0 = fmaf(h1[0][4 * q + 0], wv.x, acc0);
            acc0 = fmaf(h1[0][4 * q + 1], wv.y, acc0);
            acc0 = fmaf(h1[0][4 * q + 2], wv.z, acc0);
            acc0 = fmaf(h1[0][4 * q + 3], wv.w, acc0);
            acc1 = fmaf(h1[1][4 * q + 0], wv.x, acc1);
            acc1 = fmaf(h1[1][4 * q + 1], wv.y, acc1);
            acc1 = fmaf(h1[1][4 * q + 2], wv.z, acc1);
            acc1 = fmaf(h1[1][4 * q + 3], wv.w, acc1);
        }
        float w30 = s_pw3[2 * jj], w31 = s_pw3[2 * jj + 1];
        float r0 = fmaxf(acc0, 0.0f), r1 = fmaxf(acc1, 0.0f);
        o3[0] = fmaf(r0, w30, o3[0]);
        o4[0] = fmaf(r0, w31, o4[0]);
        o3[1] = fmaf(r1, w30, o3[1]);
        o4[1] = fmaf(r1, w31, o4[1]);
    }
    xp[0][3] += o3[0] + s_pb3[0];
    xp[0][4] += o4[0] + s_pb3[1];
    xp[1][3] += o3[1] + s_pb3[0];
    xp[1][4] += o4[1] + s_pb3[1];

    // ---- raw-moment reductions: 15 independent butterfly chains (one phase) ----
    float red[15];
    #pragma unroll
    for (int i = 0; i < 5; ++i) red[i] = xp[0][i] + xp[1][i];
    #pragma unroll
    for (int i = 0; i < 5; ++i) {
        #pragma unroll
        for (int z = 0; z < 2; ++z)
            red[5 + 2 * i + z] = xp[0][i] * xp[0][3 + z] + xp[1][i] * xp[1][3 + z];
    }
    #pragma unroll
    for (int off = 1; off < 64; off <<= 1) {
        #pragma unroll
        for (int r = 0; r < 15; ++r)
            red[r] += __shfl_xor(red[r], off, 64);
    }

    // ---- finish noise MLP ----
    float diag0, diag1;
    {
        float acc = (na0 + na1) + (na2 + na3);
        acc += __shfl_xor(acc, 32, 64); // combine k-halves
        acc += s_nb1[j];
        float h = fmaxf(acc, 0.0f);
        float d0 = h * s_nw2[2 * j + 0];
        float d1 = h * s_nw2[2 * j + 1];
        #pragma unroll
        for (int off = 1; off < 32; off <<= 1) {
            d0 += __shfl_xor(d0, off, 64);
            d1 += __shfl_xor(d1, off, 64);
        }
        float e0 = d0 + s_nb2[0] + s_bias[0];
        float e1 = d1 + s_nb2[1] + s_bias[1];
        diag0 = fmaf(e0, e0, s_bias[2]);
        diag1 = fmaf(e1, e1, s_bias[3]);
    }

    // ---- covariances + analytic 2x2 solve ----
    const float inv  = 1.0f / 127.0f;
    const float minv = inv * 0.0078125f; // 1/(127*128)
    float S[5][2];
    #pragma unroll
    for (int i = 0; i < 5; ++i) {
        #pragma unroll
        for (int z = 0; z < 2; ++z)
            S[i][z] = red[5 + 2 * i + z] * inv - red[i] * red[3 + z] * minv;
    }
    float p00 = S[3][0] + diag0;
    float p01 = S[3][1];
    float p10 = S[4][0];
    float p11 = S[4][1] + diag1;
    float rdet = 1.0f / (p00 * p11 - p01 * p10);
    float Kt0[5], Kt1[5];
    #pragma unroll
    for (int i = 0; i < 5; ++i) {
        Kt0[i] = (p11 * S[i][0] - p01 * S[i][1]) * rdet;
        Kt1[i] = (p00 * S[i][1] - p10 * S[i][0]) * rdet;
    }

    // ---- Kalman update, direct global stores ----
    #pragma unroll
    for (int m = 0; m < 2; ++m) {
        const int p = l + 64 * m;
        const float2 yy = *(const float2*)(y_obs + (b * 128 + (size_t)p) * 2);
        float i0 = yy.x - xp[m][3];
        float i1 = yy.y - xp[m][4];
        float* o = out + (b * 128 + (size_t)p) * 5;
        #pragma unroll
        for (int i = 0; i < 5; ++i)
            o[i] = xp[m][i] + i0 * Kt0[i] + i1 * Kt1[i];
    }
}

extern "C" void kernel_launch(void* const* d_in, const int* in_sizes, int n_in,
                              void* d_out, int out_size, void* d_ws, size_t ws_size,
                              hipStream_t stream) {
    const float* state_old = (const float*)d_in[0];
    const float* y_obs     = (const float*)d_in[1];
    const float* encoding  = (const float*)d_in[2];
    const float* pw1 = (const float*)d_in[3];
    const float* pb1 = (const float*)d_in[4];
    const float* pw2 = (const float*)d_in[5];
    const float* pb2 = (const float*)d_in[6];
    const float* pw3 = (const float*)d_in[7];
    const float* pb3 = (const float*)d_in[8];
    const float* nw1 = (const float*)d_in[9];
    const float* nb1 = (const float*)d_in[10];
    const float* nw2 = (const float*)d_in[11];
    const float* nb2 = (const float*)d_in[12];
    const float* lob = (const float*)d_in[13];
    const float* fob = (const float*)d_in[14];
    float* out = (float*)d_out;

    const int B = 16384;
    dim3 grid(B / BPB);
    dim3 block(128);
    hipLaunchKernelGGL(ekf_fused, grid, block, 0, stream,
                       state_old, y_obs, encoding,
                       pw1, pb1, pw2, pb2, pw3, pb3,
                       nw1, nb1, nw2, nb2, lob, fob, out);
}

// Round 4
// 76.163 us; speedup vs baseline: 6.4598x; 6.4598x over previous
//
#include <hip/hip_runtime.h>

// EKF_v2: B=16384 batches, N=128 particles, DX=5, DZ=2.
// Round-1 structure (known-good codegen: FETCH 33MB / WRITE 41MB, no scratch)
// + __sinf/__cosf (native, return-by-value) + 4-chain noise-MLP loop.
// One block = 4 batches (512 particles), 128 threads, 4 particles/thread.
// Thread t: batch g = t>>5, lane-in-batch j = t&31, particles j+32m (m=0..3).

#define NBATCH_PER_BLOCK 4

__global__ __launch_bounds__(128) void ekf_fused(
    const float* __restrict__ state_old,  // (B,128,5)
    const float* __restrict__ y_obs,      // (B,128,2)
    const float* __restrict__ encoding,   // (B,128)
    const float* __restrict__ pw1,        // (2,16)
    const float* __restrict__ pb1,        // (16)
    const float* __restrict__ pw2,        // (16,32)
    const float* __restrict__ pb2,        // (32)
    const float* __restrict__ pw3,        // (32,2)
    const float* __restrict__ pb3,        // (2)
    const float* __restrict__ nw1,        // (128,32)
    const float* __restrict__ nb1,        // (32)
    const float* __restrict__ nw2,        // (32,2)
    const float* __restrict__ nb2,        // (2)
    const float* __restrict__ lob,        // (2)
    const float* __restrict__ fob,        // (2)
    float* __restrict__ out)              // (B,128,5)
{
    __shared__ __align__(16) float s_state[NBATCH_PER_BLOCK * 640]; // in, reused as out staging
    __shared__ __align__(16) float s_y[NBATCH_PER_BLOCK * 256];
    __shared__ __align__(16) float s_enc[NBATCH_PER_BLOCK * 128];
    __shared__ __align__(16) float s_pw2t[512]; // transposed: [j][k] = pw2[k][j]
    __shared__ float s_pw1[32];
    __shared__ float s_pb1[16];
    __shared__ float s_pb2[32];
    __shared__ float s_pw3[64];
    __shared__ float s_pb3[2];
    __shared__ float s_nb1[32];
    __shared__ float s_nw2[64];
    __shared__ float s_nb2[2];
    __shared__ float s_bias[4]; // lob0, lob1, fob0, fob1

    const int t = threadIdx.x;
    const int blk = blockIdx.x;
    const int base = blk * NBATCH_PER_BLOCK; // first batch of this block

    // ---- stage inputs (coalesced float4) ----
    {
        const float4* src = (const float4*)(state_old + (size_t)base * 640);
        float4* dst = (float4*)s_state;
        #pragma unroll
        for (int i = t; i < 640; i += 128) dst[i] = src[i];
        const float4* sy = (const float4*)(y_obs + (size_t)base * 256);
        float4* dy = (float4*)s_y;
        #pragma unroll
        for (int i = t; i < 256; i += 128) dy[i] = sy[i];
        const float4* se = (const float4*)(encoding + (size_t)base * 128);
        float4* de = (float4*)s_enc;
        if (t < 128) de[t] = se[t];
    }
    // ---- stage weights ----
    if (t < 32) { s_pw1[t] = pw1[t]; s_pb2[t] = pb2[t]; s_nb1[t] = nb1[t]; }
    if (t < 16) s_pb1[t] = pb1[t];
    if (t < 64) { s_pw3[t] = pw3[t]; s_nw2[t] = nw2[t]; }
    if (t < 2)  { s_pb3[t] = pb3[t]; s_nb2[t] = nb2[t]; s_bias[t] = lob[t]; s_bias[2 + t] = fob[t]; }
    for (int i = t; i < 512; i += 128) { int j = i >> 4, k = i & 15; s_pw2t[i] = pw2[k * 32 + j]; }
    __syncthreads();

    const int g = t >> 5;     // batch within block
    const int j32 = t & 31;   // lane within batch group

    // ---- noise MLP: diag (per batch); 4 independent FMA chains ----
    float diag0, diag1;
    {
        const float* eg = s_enc + g * 128;
        const float* w = nw1 + j32;
        float a0 = 0.0f, a1 = 0.0f, a2 = 0.0f, a3 = 0.0f;
        #pragma unroll 4
        for (int k = 0; k < 128; k += 4) {
            a0 = fmaf(eg[k + 0], w[(k + 0) * 32], a0);
            a1 = fmaf(eg[k + 1], w[(k + 1) * 32], a1);
            a2 = fmaf(eg[k + 2], w[(k + 2) * 32], a2);
            a3 = fmaf(eg[k + 3], w[(k + 3) * 32], a3);
        }
        float acc = ((a0 + a1) + (a2 + a3)) + s_nb1[j32];
        float h = fmaxf(acc, 0.0f);
        float d0 = h * s_nw2[j32 * 2 + 0];
        float d1 = h * s_nw2[j32 * 2 + 1];
        #pragma unroll
        for (int off = 1; off < 32; off <<= 1) {
            d0 += __shfl_xor(d0, off, 64);
            d1 += __shfl_xor(d1, off, 64);
        }
        d0 += s_nb2[0]; d1 += s_nb2[1];
        float e0 = d0 + s_bias[0], e1 = d1 + s_bias[1];
        diag0 = fmaf(e0, e0, s_bias[2]);
        diag1 = fmaf(e1, e1, s_bias[3]);
    }

    // ---- process model: 4 particles/thread ----
    float xp[4][5];
    float h1[4][16];
    #pragma unroll
    for (int m = 0; m < 4; ++m) {
        const float* s = s_state + g * 640 + (j32 + 32 * m) * 5;
        float s0 = s[0], s1 = s[1], s2 = s[2], v = s[3], td = s[4];
        float theta = s2 + td;
        float sn = __sinf(theta);
        float cs = __cosf(theta);
        xp[m][0] = fmaf(v, sn, s0);
        xp[m][1] = fmaf(v, cs, s1);
        xp[m][2] = theta;
        xp[m][3] = v;   // data_out accumulates on top
        xp[m][4] = td;
        #pragma unroll
        for (int j = 0; j < 16; ++j)
            h1[m][j] = fmaxf(0.0f, fmaf(v, s_pw1[j], fmaf(td, s_pw1[16 + j], s_pb1[j])));
    }

    // ---- layers 2+3 fused: h2 = relu(h1@pw2+pb2); out += h2@pw3 ----
    float o3[4], o4[4];
    #pragma unroll
    for (int m = 0; m < 4; ++m) { o3[m] = 0.0f; o4[m] = 0.0f; }
    const float4* w2v = (const float4*)s_pw2t;
    #pragma unroll
    for (int j = 0; j < 32; ++j) {
        float acc[4];
        #pragma unroll
        for (int m = 0; m < 4; ++m) acc[m] = s_pb2[j];
        #pragma unroll
        for (int q = 0; q < 4; ++q) {
            float4 w = w2v[j * 4 + q];
            #pragma unroll
            for (int m = 0; m < 4; ++m) {
                acc[m] = fmaf(h1[m][4 * q + 0], w.x, acc[m]);
                acc[m] = fmaf(h1[m][4 * q + 1], w.y, acc[m]);
                acc[m] = fmaf(h1[m][4 * q + 2], w.z, acc[m]);
                acc[m] = fmaf(h1[m][4 * q + 3], w.w, acc[m]);
            }
        }
        float w30 = s_pw3[2 * j], w31 = s_pw3[2 * j + 1];
        #pragma unroll
        for (int m = 0; m < 4; ++m) {
            float r = fmaxf(acc[m], 0.0f);
            o3[m] = fmaf(r, w30, o3[m]);
            o4[m] = fmaf(r, w31, o4[m]);
        }
    }
    #pragma unroll
    for (int m = 0; m < 4; ++m) {
        xp[m][3] += o3[m] + s_pb3[0];
        xp[m][4] += o4[m] + s_pb3[1];
    }

    // ---- per-batch means (butterfly over 32 lanes; all lanes identical) ----
    float mean[5];
    #pragma unroll
    for (int i = 0; i < 5; ++i) {
        float ps = (xp[0][i] + xp[1][i]) + (xp[2][i] + xp[3][i]);
        #pragma unroll
        for (int off = 1; off < 32; off <<= 1) ps += __shfl_xor(ps, off, 64);
        mean[i] = ps * 0.0078125f; // /128 exact
    }

    float A[4][5];
    #pragma unroll
    for (int m = 0; m < 4; ++m)
        #pragma unroll
        for (int i = 0; i < 5; ++i) A[m][i] = xp[m][i] - mean[i];

    // ---- cross-moments S[i][z] = sum_n A[n][i]*A[n][3+z] ----
    float S[5][2];
    #pragma unroll
    for (int i = 0; i < 5; ++i) {
        #pragma unroll
        for (int z = 0; z < 2; ++z) {
            float ps = (A[0][i] * A[0][3 + z] + A[1][i] * A[1][3 + z])
                     + (A[2][i] * A[2][3 + z] + A[3][i] * A[3][3 + z]);
            #pragma unroll
            for (int off = 1; off < 32; off <<= 1) ps += __shfl_xor(ps, off, 64);
            S[i][z] = ps;
        }
    }

    // ---- 2x2 solve: Kt = Pzz^{-1} @ Pxz^T ----
    const float inv_denom = 1.0f / 127.0f;
    float p00 = fmaf(S[3][0], inv_denom, diag0);
    float p01 = S[3][1] * inv_denom;
    float p10 = S[4][0] * inv_denom;
    float p11 = fmaf(S[4][1], inv_denom, diag1);
    float det = p00 * p11 - p01 * p10;
    float rdet = 1.0f / det;
    float Kt0[5], Kt1[5];
    #pragma unroll
    for (int i = 0; i < 5; ++i) {
        float b0 = S[i][0] * inv_denom; // Pxz[i][0]
        float b1 = S[i][1] * inv_denom; // Pxz[i][1]
        Kt0[i] = (p11 * b0 - p01 * b1) * rdet;
        Kt1[i] = (p00 * b1 - p10 * b0) * rdet;
    }

    // ---- Kalman update; stage output in s_state (each thread owns its slots) ----
    __syncthreads(); // all reads of s_state done before overwrite
    #pragma unroll
    for (int m = 0; m < 4; ++m) {
        const float* yy = s_y + g * 256 + (j32 + 32 * m) * 2;
        float i0 = yy[0] - xp[m][3];
        float i1 = yy[1] - xp[m][4];
        float* o = s_state + g * 640 + (j32 + 32 * m) * 5;
        #pragma unroll
        for (int i = 0; i < 5; ++i)
            o[i] = xp[m][i] + i0 * Kt0[i] + i1 * Kt1[i];
    }
    __syncthreads();
    {
        const float4* src = (const float4*)s_state;
        float4* dst = (float4*)(out + (size_t)base * 640);
        #pragma unroll
        for (int i = t; i < 640; i += 128) dst[i] = src[i];
    }
}

extern "C" void kernel_launch(void* const* d_in, const int* in_sizes, int n_in,
                              void* d_out, int out_size, void* d_ws, size_t ws_size,
                              hipStream_t stream) {
    const float* state_old = (const float*)d_in[0];
    const float* y_obs     = (const float*)d_in[1];
    const float* encoding  = (const float*)d_in[2];
    const float* pw1 = (const float*)d_in[3];
    const float* pb1 = (const float*)d_in[4];
    const float* pw2 = (const float*)d_in[5];
    const float* pb2 = (const float*)d_in[6];
    const float* pw3 = (const float*)d_in[7];
    const float* pb3 = (const float*)d_in[8];
    const float* nw1 = (const float*)d_in[9];
    const float* nb1 = (const float*)d_in[10];
    const float* nw2 = (const float*)d_in[11];
    const float* nb2 = (const float*)d_in[12];
    const float* lob = (const float*)d_in[13];
    const float* fob = (const float*)d_in[14];
    float* out = (float*)d_out;

    const int B = 16384;
    dim3 grid(B / NBATCH_PER_BLOCK);
    dim3 block(128);
    hipLaunchKernelGGL(ekf_fused, grid, block, 0, stream,
                       state_old, y_obs, encoding,
                       pw1, pb1, pw2, pb2, pw3, pb3,
                       nw1, nb1, nw2, nb2, lob, fob, out);
}